// Round 1
// baseline (10794.317 us; speedup 1.0000x reference)
//
#include <hip/hip_runtime.h>

#define BATCH_N 16384
#define DM 512
#define NPOS 9

// ---------------------------------------------------------------------------
// K1/K4: out[b,n] = sum_e A[b*lda + aoff + e] * W[n*512 + e] + bias[n]
// Tile: M=128, N=64, K=64. 256 threads, each 8x4 outputs.
// ---------------------------------------------------------------------------
__global__ __launch_bounds__(256) void gemm_bias_k(
    const float* __restrict__ A, int lda, int aoff,
    const float* __restrict__ Wt, const float* __restrict__ bias,
    float* __restrict__ out)
{
    __shared__ float As[64][130];  // [k][m], m=0..127
    __shared__ float Ws[64][66];   // [k][n], n=0..63
    const int t  = threadIdx.x;
    const int tx = t & 15;         // n lane
    const int ty = t >> 4;         // m base
    const int b0 = blockIdx.x * 128;
    const int n0 = blockIdx.y * 64;

    float acc[8][4] = {};
    for (int k0 = 0; k0 < 512; k0 += 64) {
#pragma unroll
        for (int rr = 0; rr < 8; ++rr) {
            const int row = ty + 16 * rr;  // 0..127
            const float4 va = *(const float4*)&A[(size_t)(b0 + row) * lda + aoff + k0 + tx * 4];
            As[tx*4+0][row] = va.x; As[tx*4+1][row] = va.y;
            As[tx*4+2][row] = va.z; As[tx*4+3][row] = va.w;
            if (rr < 4) {
                const float4 vw = *(const float4*)&Wt[(size_t)(n0 + row) * 512 + k0 + tx * 4];
                Ws[tx*4+0][row] = vw.x; Ws[tx*4+1][row] = vw.y;
                Ws[tx*4+2][row] = vw.z; Ws[tx*4+3][row] = vw.w;
            }
        }
        __syncthreads();
#pragma unroll 8
        for (int kk = 0; kk < 64; ++kk) {
            float a[8], w[4];
#pragma unroll
            for (int i = 0; i < 8; ++i) a[i] = As[kk][ty + 16*i];
#pragma unroll
            for (int j = 0; j < 4; ++j) w[j] = Ws[kk][tx + 16*j];
#pragma unroll
            for (int i = 0; i < 8; ++i)
#pragma unroll
                for (int j = 0; j < 4; ++j) acc[i][j] += a[i] * w[j];
        }
        __syncthreads();
    }
#pragma unroll
    for (int i = 0; i < 8; ++i)
#pragma unroll
        for (int j = 0; j < 4; ++j) {
            const int n = n0 + tx + 16*j;
            out[(size_t)(b0 + ty + 16*i) * 512 + n] = acc[i][j] + bias[n];
        }
}

// ---------------------------------------------------------------------------
// K2: fused logits. logits[b,p] += sum_n q[b,n] * (k_tile[b,n] + bk[p,n])
// Same GEMM tiling; epilogue dots with q and block-reduces to one atomicAdd
// per row. Grid: (B/128, 512/64, 9).
// ---------------------------------------------------------------------------
__global__ __launch_bounds__(256) void gemm_logits_k(
    const float* __restrict__ x, const float* __restrict__ Wk,
    const float* __restrict__ bk, const float* __restrict__ q,
    float* __restrict__ logits)
{
    __shared__ float As[64][130];
    __shared__ float Ws[64][66];
    __shared__ float red[128][17];
    const int t  = threadIdx.x;
    const int tx = t & 15;
    const int ty = t >> 4;
    const int b0 = blockIdx.x * 128;
    const int n0 = blockIdx.y * 64;
    const int p  = blockIdx.z;
    const float* W = Wk + (size_t)p * 512 * 512;

    float acc[8][4] = {};
    for (int k0 = 0; k0 < 512; k0 += 64) {
#pragma unroll
        for (int rr = 0; rr < 8; ++rr) {
            const int row = ty + 16 * rr;
            const float4 va = *(const float4*)&x[((size_t)(b0 + row) * 9 + p) * 512 + k0 + tx * 4];
            As[tx*4+0][row] = va.x; As[tx*4+1][row] = va.y;
            As[tx*4+2][row] = va.z; As[tx*4+3][row] = va.w;
            if (rr < 4) {
                const float4 vw = *(const float4*)&W[(size_t)(n0 + row) * 512 + k0 + tx * 4];
                Ws[tx*4+0][row] = vw.x; Ws[tx*4+1][row] = vw.y;
                Ws[tx*4+2][row] = vw.z; Ws[tx*4+3][row] = vw.w;
            }
        }
        __syncthreads();
#pragma unroll 8
        for (int kk = 0; kk < 64; ++kk) {
            float a[8], w[4];
#pragma unroll
            for (int i = 0; i < 8; ++i) a[i] = As[kk][ty + 16*i];
#pragma unroll
            for (int j = 0; j < 4; ++j) w[j] = Ws[kk][tx + 16*j];
#pragma unroll
            for (int i = 0; i < 8; ++i)
#pragma unroll
                for (int j = 0; j < 4; ++j) acc[i][j] += a[i] * w[j];
        }
        __syncthreads();
    }
    float rp[8] = {};
#pragma unroll
    for (int i = 0; i < 8; ++i)
#pragma unroll
        for (int j = 0; j < 4; ++j) {
            const int n = n0 + tx + 16*j;
            rp[i] += (acc[i][j] + bk[p*512 + n]) * q[(size_t)(b0 + ty + 16*i) * 512 + n];
        }
#pragma unroll
    for (int i = 0; i < 8; ++i) red[ty + 16*i][tx] = rp[i];
    __syncthreads();
    if (t < 128) {
        float s = 0.f;
#pragma unroll
        for (int u = 0; u < 16; ++u) s += red[t][u];
        atomicAdd(&logits[(size_t)(b0 + t) * 9 + p], s);
    }
}

// ---------------------------------------------------------------------------
// K3: per-row softmax over 9 logits, x_cent = sum_p a_p x[b,p,:],
// mode 0: out = l2norm(x_cent);  mode 1 (final): out = l2norm(x_cent + x[b,8,:])
// One wave per row. Grid B/4, block 256.
// ---------------------------------------------------------------------------
__global__ __launch_bounds__(256) void softmax_cent_k(
    const float* __restrict__ x, const float* __restrict__ logits,
    float* __restrict__ outp, int mode)
{
    const int lane = threadIdx.x & 63;
    const size_t b = (size_t)blockIdx.x * 4 + (threadIdx.x >> 6);
    float lg[9];
    float m = -1e30f;
#pragma unroll
    for (int p = 0; p < 9; ++p) { lg[p] = logits[b*9 + p]; m = fmaxf(m, lg[p]); }
    float s = 0.f;
#pragma unroll
    for (int p = 0; p < 9; ++p) { lg[p] = expf(lg[p] - m); s += lg[p]; }
    const float inv = 1.0f / s;
    float c[8];
    float ssq = 0.f;
#pragma unroll
    for (int i = 0; i < 8; ++i) {
        const int e = lane + 64*i;
        float a = 0.f;
#pragma unroll
        for (int p = 0; p < 9; ++p) a += lg[p] * x[(b*9 + p)*512 + e];
        a *= inv;
        if (mode) a += x[(b*9 + 8)*512 + e];
        c[i] = a; ssq += a * a;
    }
#pragma unroll
    for (int off = 32; off > 0; off >>= 1) ssq += __shfl_xor(ssq, off, 64);
    const float invn = 1.0f / fmaxf(sqrtf(ssq), 1e-12f);
#pragma unroll
    for (int i = 0; i < 8; ++i) outp[b*512 + lane + 64*i] = c[i] * invn;
}

// ---------------------------------------------------------------------------
// K5: x[b,8,:] = l2norm(y[b,:] + x[b,8,:]). One wave per row.
// ---------------------------------------------------------------------------
__global__ __launch_bounds__(256) void resid_k(
    float* __restrict__ x, const float* __restrict__ y)
{
    const int lane = threadIdx.x & 63;
    const size_t b = (size_t)blockIdx.x * 4 + (threadIdx.x >> 6);
    float c[8];
    float ssq = 0.f;
#pragma unroll
    for (int i = 0; i < 8; ++i) {
        const int e = lane + 64*i;
        const float v = y[b*512 + e] + x[(b*9 + 8)*512 + e];
        c[i] = v; ssq += v * v;
    }
#pragma unroll
    for (int off = 32; off > 0; off >>= 1) ssq += __shfl_xor(ssq, off, 64);
    const float invn = 1.0f / fmaxf(sqrtf(ssq), 1e-12f);
#pragma unroll
    for (int i = 0; i < 8; ++i) x[(b*9 + 8)*512 + lane + 64*i] = c[i] * invn;
}

// ---------------------------------------------------------------------------
// K6: window, IN-PLACE: x[b,p,:] = l2norm(x[b,p,:]@Wfw[p].T + bfw[p] + x[b,p,:])
// for p<8. Block stages its 16 full rows in LDS first (write-set == staged
// read-set -> in-place safe), computes all 512 cols (2 chunks x 256),
// fuses bias+residual+l2norm (in-wave reduce; row lives in one wave).
// Grid (B/16, 8), block 256: ty=t>>6 (wave -> rows 4ty..4ty+3), tx=t&63.
// ---------------------------------------------------------------------------
__global__ __launch_bounds__(256) void window_k(
    float* __restrict__ x, const float* __restrict__ Wfw,
    const float* __restrict__ bfw)
{
    __shared__ float xin[16][516];   // [row][k], full K staged
    __shared__ float Wt[16][260];    // [k][n-chunk], ktile=16, 256 cols
    const int t  = threadIdx.x;
    const int tx = t & 63;
    const int ty = t >> 6;           // 0..3
    const int p  = blockIdx.y;
    const int b0 = blockIdx.x * 16;
    const float* W = Wfw + (size_t)p * 512 * 512;

    // stage 16 input rows
#pragma unroll
    for (int ii = 0; ii < 8; ++ii) {
        const int idx = t + 256 * ii;     // 0..2047 float4 slots
        const int row = idx >> 7;         // 0..15
        const int c4  = idx & 127;        // 0..127
        const float4 v = *(const float4*)&x[((size_t)(b0 + row) * 9 + p) * 512 + c4 * 4];
        *(float4*)&xin[row][c4 * 4] = v;
    }
    __syncthreads();

    float acc[2][4][4] = {};
    for (int c2 = 0; c2 < 2; ++c2) {
        for (int k0 = 0; k0 < 512; k0 += 16) {
#pragma unroll
            for (int ii = 0; ii < 4; ++ii) {
                const int idx = t + 256 * ii;  // 0..1023
                const int n  = idx >> 2;       // 0..255
                const int c4 = idx & 3;        // 0..3 -> k cols c4*4..c4*4+3
                const float4 v = *(const float4*)&W[(size_t)(c2*256 + n) * 512 + k0 + c4 * 4];
                Wt[c4*4+0][n] = v.x; Wt[c4*4+1][n] = v.y;
                Wt[c4*4+2][n] = v.z; Wt[c4*4+3][n] = v.w;
            }
            __syncthreads();
#pragma unroll
            for (int kk = 0; kk < 16; ++kk) {
                float a[4], w[4];
#pragma unroll
                for (int i = 0; i < 4; ++i) a[i] = xin[4*ty + i][k0 + kk];
#pragma unroll
                for (int j = 0; j < 4; ++j) w[j] = Wt[kk][tx + 64*j];
#pragma unroll
                for (int i = 0; i < 4; ++i)
#pragma unroll
                    for (int j = 0; j < 4; ++j) acc[c2][i][j] += a[i] * w[j];
            }
            __syncthreads();
        }
    }

    // epilogue: bias + residual, per-row l2norm (row == one wave), in-place write
#pragma unroll
    for (int i = 0; i < 4; ++i) {
        const int m = 4*ty + i;
        float ssq = 0.f;
#pragma unroll
        for (int c2 = 0; c2 < 2; ++c2)
#pragma unroll
            for (int j = 0; j < 4; ++j) {
                const int n = c2*256 + tx + 64*j;
                const float v = acc[c2][i][j] + bfw[p*512 + n] + xin[m][n];
                acc[c2][i][j] = v;
                ssq += v * v;
            }
#pragma unroll
        for (int off = 32; off > 0; off >>= 1) ssq += __shfl_xor(ssq, off, 64);
        const float invn = 1.0f / fmaxf(sqrtf(ssq), 1e-12f);
#pragma unroll
        for (int c2 = 0; c2 < 2; ++c2)
#pragma unroll
            for (int j = 0; j < 4; ++j) {
                const int n = c2*256 + tx + 64*j;
                x[((size_t)(b0 + m) * 9 + p) * 512 + n] = acc[c2][i][j] * invn;
            }
    }
}

// ---------------------------------------------------------------------------
extern "C" void kernel_launch(void* const* d_in, const int* in_sizes, int n_in,
                              void* d_out, int out_size, void* d_ws, size_t ws_size,
                              hipStream_t stream) {
    (void)in_sizes; (void)n_in; (void)out_size; (void)ws_size;
    float* x = (float*)d_in[0];   // mutated in place; harness restores per launch
    const float* Wq  = (const float*)d_in[1];
    const float* bq  = (const float*)d_in[2];
    const float* Wk  = (const float*)d_in[3];
    const float* bk  = (const float*)d_in[4];
    const float* Wfw = (const float*)d_in[5];
    const float* bfw = (const float*)d_in[6];
    const float* Wfc = (const float*)d_in[7];
    const float* bfc = (const float*)d_in[8];
    const float* Wqf = (const float*)d_in[9];
    const float* bqf = (const float*)d_in[10];
    const float* Wkf = (const float*)d_in[11];
    const float* bkf = (const float*)d_in[12];
    float* out = (float*)d_out;

    float* q      = (float*)d_ws;                  // B*512
    float* cent   = q    + (size_t)BATCH_N * 512;  // B*512
    float* y      = cent + (size_t)BATCH_N * 512;  // B*512
    float* logits = y    + (size_t)BATCH_N * 512;  // B*9

    const dim3 gemm_grid(BATCH_N / 128, 8);
    const dim3 log_grid(BATCH_N / 128, 8, 9);

    for (int l = 0; l < 3; ++l) {
        gemm_bias_k<<<gemm_grid, 256, 0, stream>>>(
            x, 9*512, 8*512, Wq + (size_t)l*512*512, bq + l*512, q);
        hipMemsetAsync(logits, 0, (size_t)BATCH_N * 9 * sizeof(float), stream);
        gemm_logits_k<<<log_grid, 256, 0, stream>>>(
            x, Wk + (size_t)l*9*512*512, bk + l*9*512, q, logits);
        softmax_cent_k<<<BATCH_N/4, 256, 0, stream>>>(x, logits, cent, 0);
        gemm_bias_k<<<gemm_grid, 256, 0, stream>>>(
            cent, 512, 0, Wfc + (size_t)l*512*512, bfc + l*512, y);
        resid_k<<<BATCH_N/4, 256, 0, stream>>>(x, y);
        window_k<<<dim3(BATCH_N/16, 8), 256, 0, stream>>>(
            x, Wfw + (size_t)l*8*512*512, bfw + l*8*512);
    }
    // final attention -> output
    gemm_bias_k<<<gemm_grid, 256, 0, stream>>>(x, 9*512, 8*512, Wqf, bqf, q);
    hipMemsetAsync(logits, 0, (size_t)BATCH_N * 9 * sizeof(float), stream);
    gemm_logits_k<<<log_grid, 256, 0, stream>>>(x, Wkf, bkf, q, logits);
    softmax_cent_k<<<BATCH_N/4, 256, 0, stream>>>(x, logits, out, 1);
}

// Round 2
// 3075.003 us; speedup vs baseline: 3.5103x; 3.5103x over previous
//
#include <hip/hip_runtime.h>

#define BATCH_N 16384
#define PLANE 262144          // 512*512 elements per weight matrix
typedef unsigned short ushort_t;
typedef __attribute__((ext_vector_type(4))) float f32x4;
typedef __attribute__((ext_vector_type(8))) short s16x8;
typedef __attribute__((ext_vector_type(4))) unsigned short u16x4;

// Cheap truncating hi/lo bf16 split: v ~= hi + lo to ~2^-16 relative.
__device__ inline void split_bf(float f, ushort_t& h, ushort_t& l) {
    unsigned u = __float_as_uint(f);
    h = (ushort_t)(u >> 16);
    float fh = __uint_as_float(u & 0xFFFF0000u);
    float r = f - fh;
    l = (ushort_t)(__float_as_uint(r) >> 16);
}

// ---------------------------------------------------------------------------
// Weight conversion: fp32 -> hi/lo bf16 planes. One float4 per thread.
// ---------------------------------------------------------------------------
__global__ __launch_bounds__(256) void convert_w_k(
    const float* __restrict__ src, ushort_t* __restrict__ hi,
    ushort_t* __restrict__ lo, int n4)
{
    const int i = blockIdx.x * 256 + threadIdx.x;
    if (i >= n4) return;
    const f32x4 v = ((const f32x4*)src)[i];
    ushort_t h[4], l[4];
#pragma unroll
    for (int u = 0; u < 4; ++u) split_bf(v[u], h[u], l[u]);
    *(u16x4*)&hi[(size_t)i * 4] = (u16x4){h[0], h[1], h[2], h[3]};
    *(u16x4*)&lo[(size_t)i * 4] = (u16x4){l[0], l[1], l[2], l[3]};
}

// ---------------------------------------------------------------------------
// Split-bf16 MFMA GEMM, tile 128x128, BK=32, 4 waves of 64x64.
// out[m][n] = sum_k A[m][k] * W[n][k]  (+ bias / logits epilogue)
// A fp32 (converted to hi/lo during staging); W pre-split bf16 planes.
// EPI=0: out = acc + bias[n]          (grid.z = 1)
// EPI=1: logits[b][p] += sum_n (acc + bk[p][n]) * q[b][n]   (grid.z = 9)
// MFMA 16x16x32 layouts (verified):
//   A/B frag: row/col = lane&15, k = (lane>>4)*8 + j
//   C/D:      col = lane&15, row = (lane>>4)*4 + reg
// ---------------------------------------------------------------------------
template <int EPI>
__global__ __launch_bounds__(256, 3) void mfma_gemm_k(
    const float* __restrict__ A, int lda, int aoff,
    const ushort_t* __restrict__ Wh, const ushort_t* __restrict__ Wl,
    const float* __restrict__ bias, float* __restrict__ outp,
    const float* __restrict__ q, float* __restrict__ logits)
{
    __shared__ __align__(16) ushort_t Ah[128 * 40];
    __shared__ __align__(16) ushort_t Al[128 * 40];
    __shared__ __align__(16) ushort_t Bh[128 * 40];
    __shared__ __align__(16) ushort_t Bl[128 * 40];

    const int t = threadIdx.x;
    const int lane = t & 63, wave = t >> 6;
    const int wm = (wave >> 1) * 64, wn = (wave & 1) * 64;
    const int quad = lane >> 4, l15 = lane & 15;
    const size_t b0 = (size_t)blockIdx.x * 128;
    const int n0 = blockIdx.y * 128;
    int p = 0;
    if (EPI == 1) {
        p = blockIdx.z;
        Wh += (size_t)PLANE * p;
        Wl += (size_t)PLANE * p;
        aoff += p * 512;
    }

    f32x4 acc[4][4] = {};

    for (int k0 = 0; k0 < 512; k0 += 32) {
        // ---- global prefetch into registers
        f32x4 av[4];
        s16x8 bhv[2], blv[2];
#pragma unroll
        for (int u = 0; u < 4; ++u) {
            const int f = t + 256 * u, row = f >> 3, c = f & 7;
            av[u] = *(const f32x4*)&A[(b0 + row) * lda + aoff + k0 + c * 4];
        }
#pragma unroll
        for (int u = 0; u < 2; ++u) {
            const int f = t + 256 * u, row = f >> 2, c = f & 3;
            bhv[u] = *(const s16x8*)&Wh[(size_t)(n0 + row) * 512 + k0 + c * 8];
            blv[u] = *(const s16x8*)&Wl[(size_t)(n0 + row) * 512 + k0 + c * 8];
        }
        __syncthreads();
        // ---- stage to LDS (A converted to hi/lo)
#pragma unroll
        for (int u = 0; u < 4; ++u) {
            const int f = t + 256 * u, row = f >> 3, c = f & 7;
            ushort_t h[4], l[4];
#pragma unroll
            for (int e = 0; e < 4; ++e) split_bf(av[u][e], h[e], l[e]);
            *(u16x4*)&Ah[row * 40 + c * 4] = (u16x4){h[0], h[1], h[2], h[3]};
            *(u16x4*)&Al[row * 40 + c * 4] = (u16x4){l[0], l[1], l[2], l[3]};
        }
#pragma unroll
        for (int u = 0; u < 2; ++u) {
            const int f = t + 256 * u, row = f >> 2, c = f & 3;
            *(s16x8*)&Bh[row * 40 + c * 8] = bhv[u];
            *(s16x8*)&Bl[row * 40 + c * 8] = blv[u];
        }
        __syncthreads();
        // ---- MFMA: 16 tiles x 3 split-products
        s16x8 ah[4], alo[4];
#pragma unroll
        for (int i = 0; i < 4; ++i) {
            ah[i]  = *(const s16x8*)&Ah[(wm + i * 16 + l15) * 40 + quad * 8];
            alo[i] = *(const s16x8*)&Al[(wm + i * 16 + l15) * 40 + quad * 8];
        }
#pragma unroll
        for (int j = 0; j < 4; ++j) {
            const s16x8 bh = *(const s16x8*)&Bh[(wn + j * 16 + l15) * 40 + quad * 8];
            const s16x8 bl = *(const s16x8*)&Bl[(wn + j * 16 + l15) * 40 + quad * 8];
#pragma unroll
            for (int i = 0; i < 4; ++i) {
                acc[i][j] = __builtin_amdgcn_mfma_f32_16x16x32_bf16(ah[i], bh, acc[i][j], 0, 0, 0);
                acc[i][j] = __builtin_amdgcn_mfma_f32_16x16x32_bf16(ah[i], bl, acc[i][j], 0, 0, 0);
                acc[i][j] = __builtin_amdgcn_mfma_f32_16x16x32_bf16(alo[i], bh, acc[i][j], 0, 0, 0);
            }
        }
    }

    if (EPI == 0) {
#pragma unroll
        for (int i = 0; i < 4; ++i) {
            const int gm0 = (int)b0 + wm + i * 16 + quad * 4;
#pragma unroll
            for (int j = 0; j < 4; ++j) {
                const int gn = n0 + wn + j * 16 + l15;
                const float bv = bias[gn];
#pragma unroll
                for (int r = 0; r < 4; ++r)
                    outp[(size_t)(gm0 + r) * 512 + gn] = acc[i][j][r] + bv;
            }
        }
    } else {
        float rp[4][4] = {};
#pragma unroll
        for (int i = 0; i < 4; ++i) {
            const int gm0 = (int)b0 + wm + i * 16 + quad * 4;
#pragma unroll
            for (int j = 0; j < 4; ++j) {
                const int gn = n0 + wn + j * 16 + l15;
                const float bv = bias[(size_t)p * 512 + gn];
#pragma unroll
                for (int r = 0; r < 4; ++r)
                    rp[i][r] += (acc[i][j][r] + bv) * q[(size_t)(gm0 + r) * 512 + gn];
            }
        }
#pragma unroll
        for (int m = 1; m < 16; m <<= 1)
#pragma unroll
            for (int i = 0; i < 4; ++i)
#pragma unroll
                for (int r = 0; r < 4; ++r)
                    rp[i][r] += __shfl_xor(rp[i][r], m, 64);
        if (l15 == 0) {
#pragma unroll
            for (int i = 0; i < 4; ++i) {
                const int gm0 = (int)b0 + wm + i * 16 + quad * 4;
#pragma unroll
                for (int r = 0; r < 4; ++r)
                    atomicAdd(&logits[(size_t)(gm0 + r) * 9 + p], rp[i][r]);
            }
        }
    }
}

// ---------------------------------------------------------------------------
// softmax over 9 logits; cent = sum_p a_p x[b,p,:];
// mode 0: out = cent (normalized later via fc path? no: l2norm here)
// mode 1: out = l2norm(cent + x[b,8,:])   (final)
// ---------------------------------------------------------------------------
__global__ __launch_bounds__(256) void softmax_cent_k(
    const float* __restrict__ x, const float* __restrict__ logits,
    float* __restrict__ outp, int mode)
{
    const int lane = threadIdx.x & 63;
    const size_t b = (size_t)blockIdx.x * 4 + (threadIdx.x >> 6);
    float lg[9], m = -1e30f;
#pragma unroll
    for (int p = 0; p < 9; ++p) { lg[p] = logits[b * 9 + p]; m = fmaxf(m, lg[p]); }
    float s = 0.f;
#pragma unroll
    for (int p = 0; p < 9; ++p) { lg[p] = __expf(lg[p] - m); s += lg[p]; }
    const float inv = 1.0f / s;
    f32x4 c[2];
    float ssq = 0.f;
#pragma unroll
    for (int v = 0; v < 2; ++v) {
        f32x4 a = {0.f, 0.f, 0.f, 0.f};
#pragma unroll
        for (int p = 0; p < 9; ++p) {
            const f32x4 xv = ((const f32x4*)&x[(b * 9 + p) * 512])[v * 64 + lane];
            a += lg[p] * xv;
        }
        a *= inv;
        if (mode) a += ((const f32x4*)&x[(b * 9 + 8) * 512])[v * 64 + lane];
        c[v] = a;
        ssq += a[0]*a[0] + a[1]*a[1] + a[2]*a[2] + a[3]*a[3];
    }
#pragma unroll
    for (int off = 32; off > 0; off >>= 1) ssq += __shfl_xor(ssq, off, 64);
    const float invn = 1.0f / fmaxf(sqrtf(ssq), 1e-12f);
#pragma unroll
    for (int v = 0; v < 2; ++v)
        ((f32x4*)&outp[b * 512])[v * 64 + lane] = c[v] * invn;
}

// ---------------------------------------------------------------------------
// dst_row = l2norm(dst_row + src_row); dst stride in floats, src stride 512.
// ---------------------------------------------------------------------------
__global__ __launch_bounds__(256) void resid_norm_k(
    float* __restrict__ dst, int dstride, const float* __restrict__ src)
{
    const int lane = threadIdx.x & 63;
    const size_t b = (size_t)blockIdx.x * 4 + (threadIdx.x >> 6);
    f32x4* d4 = (f32x4*)&dst[b * (size_t)dstride];
    const f32x4* s4 = (const f32x4*)&src[b * 512];
    f32x4 a[2];
    float ssq = 0.f;
#pragma unroll
    for (int v = 0; v < 2; ++v) {
        a[v] = d4[v * 64 + lane] + s4[v * 64 + lane];
        ssq += a[v][0]*a[v][0] + a[v][1]*a[v][1] + a[v][2]*a[v][2] + a[v][3]*a[v][3];
    }
#pragma unroll
    for (int off = 32; off > 0; off >>= 1) ssq += __shfl_xor(ssq, off, 64);
    const float invn = 1.0f / fmaxf(sqrtf(ssq), 1e-12f);
#pragma unroll
    for (int v = 0; v < 2; ++v) d4[v * 64 + lane] = a[v] * invn;
}

// ---------------------------------------------------------------------------
extern "C" void kernel_launch(void* const* d_in, const int* in_sizes, int n_in,
                              void* d_out, int out_size, void* d_ws, size_t ws_size,
                              hipStream_t stream) {
    (void)in_sizes; (void)n_in; (void)out_size; (void)ws_size;
    float* x = (float*)d_in[0];   // mutated in place; harness restores per launch
    const float* Wq  = (const float*)d_in[1];
    const float* bq  = (const float*)d_in[2];
    const float* Wk  = (const float*)d_in[3];
    const float* bk  = (const float*)d_in[4];
    const float* Wfw = (const float*)d_in[5];
    const float* bfw = (const float*)d_in[6];
    const float* Wfc = (const float*)d_in[7];
    const float* bfc = (const float*)d_in[8];
    const float* Wqf = (const float*)d_in[9];
    const float* bqf = (const float*)d_in[10];
    const float* Wkf = (const float*)d_in[11];
    const float* bkf = (const float*)d_in[12];
    float* out = (float*)d_out;

    // ws layout: [hi planes | lo planes | q | cent(=tmp) | y | logits]
    ushort_t* whi = (ushort_t*)d_ws;
    ushort_t* wlo = whi + (size_t)67 * PLANE;
    float* fbuf   = (float*)(wlo + (size_t)67 * PLANE);
    float* q      = fbuf;                          // B*512
    float* cent   = q    + (size_t)BATCH_N * 512;  // B*512 (reused as window tmp)
    float* y      = cent + (size_t)BATCH_N * 512;  // B*512
    float* logits = y    + (size_t)BATCH_N * 512;  // B*9
    float* tmp    = cent;

    // plane offsets (units of PLANE): Wq 0(3), Wk 3(27), Wfw 30(24), Wfc 54(3),
    // Wqf 57(1), Wkf 58(9)
    const size_t OWq = 0, OWk = 3, OWfw = 30, OWfc = 54, OWqf = 57, OWkf = 58;

    // ---- one-time (per launch) weight split
    struct { const float* s; size_t off; int cnt; } cv[6] = {
        {Wq, OWq, 3}, {Wk, OWk, 27}, {Wfw, OWfw, 24},
        {Wfc, OWfc, 3}, {Wqf, OWqf, 1}, {Wkf, OWkf, 9}};
    for (int i = 0; i < 6; ++i) {
        const int n4 = cv[i].cnt * PLANE / 4;
        convert_w_k<<<(n4 + 255) / 256, 256, 0, stream>>>(
            cv[i].s, whi + cv[i].off * PLANE, wlo + cv[i].off * PLANE, n4);
    }

    const dim3 gemm_grid(BATCH_N / 128, 4);
    const dim3 log_grid(BATCH_N / 128, 4, 9);
    const int ew_grid = BATCH_N / 4;

    for (int l = 0; l < 3; ++l) {
        // q = x[:,8,:] @ Wq^T + bq
        mfma_gemm_k<0><<<gemm_grid, 256, 0, stream>>>(
            x, 9 * 512, 8 * 512,
            whi + (OWq + l) * PLANE, wlo + (OWq + l) * PLANE,
            bq + l * 512, q, nullptr, nullptr);
        // logits
        hipMemsetAsync(logits, 0, (size_t)BATCH_N * 9 * sizeof(float), stream);
        mfma_gemm_k<1><<<log_grid, 256, 0, stream>>>(
            x, 9 * 512, 0,
            whi + (OWk + (size_t)l * 9) * PLANE, wlo + (OWk + (size_t)l * 9) * PLANE,
            bk + (size_t)l * 9 * 512, nullptr, q, logits);
        // cent = l2norm(softmax-weighted sum)
        softmax_cent_k<<<ew_grid, 256, 0, stream>>>(x, logits, cent, 0);
        // y = cent @ Wfc^T + bfc
        mfma_gemm_k<0><<<gemm_grid, 256, 0, stream>>>(
            cent, 512, 0,
            whi + (OWfc + l) * PLANE, wlo + (OWfc + l) * PLANE,
            bfc + l * 512, y, nullptr, nullptr);
        // x[:,8,:] = l2norm(x[:,8,:] + y)
        resid_norm_k<<<ew_grid, 256, 0, stream>>>(x + 8 * 512, 9 * 512, y);
        // window: per p, tmp = x[:,p,:]@Wfw[p]^T + bfw[p]; x[:,p,:]=l2norm(x+tmp)
        for (int p = 0; p < 8; ++p) {
            mfma_gemm_k<0><<<gemm_grid, 256, 0, stream>>>(
                x, 9 * 512, p * 512,
                whi + (OWfw + (size_t)l * 8 + p) * PLANE,
                wlo + (OWfw + (size_t)l * 8 + p) * PLANE,
                bfw + ((size_t)l * 8 + p) * 512, tmp, nullptr, nullptr);
            resid_norm_k<<<ew_grid, 256, 0, stream>>>(x + p * 512, 9 * 512, tmp);
        }
    }
    // final attention -> out
    mfma_gemm_k<0><<<gemm_grid, 256, 0, stream>>>(
        x, 9 * 512, 8 * 512, whi + OWqf * PLANE, wlo + OWqf * PLANE,
        bqf, q, nullptr, nullptr);
    hipMemsetAsync(logits, 0, (size_t)BATCH_N * 9 * sizeof(float), stream);
    mfma_gemm_k<1><<<log_grid, 256, 0, stream>>>(
        x, 9 * 512, 0, whi + OWkf * PLANE, wlo + OWkf * PLANE,
        bkf, nullptr, q, logits);
    softmax_cent_k<<<ew_grid, 256, 0, stream>>>(x, logits, out, 1);
}